// Round 1
// baseline (1452.241 us; speedup 1.0000x reference)
//
#include <hip/hip_runtime.h>
#include <math.h>

#define IN_DIM 256
#define OUT_DIM 64

// ---------------------------------------------------------------------------
// K1: degree histogram. One thread per edge; fp32 atomics (device scope).
// ---------------------------------------------------------------------------
__global__ void deg_kernel(const int* __restrict__ src, const int* __restrict__ dst,
                           float* __restrict__ deg_src, float* __restrict__ deg_dst,
                           int n_edges) {
    int e = blockIdx.x * blockDim.x + threadIdx.x;
    if (e < n_edges) {
        atomicAdd(&deg_src[src[e]], 1.0f);
        atomicAdd(&deg_dst[dst[e]], 1.0f);
    }
}

// ---------------------------------------------------------------------------
// K2: m[row] = (h[row] @ W) * rsqrt(max(out_deg[row],1))
// W staged in LDS (64 KB). Block = 256 threads = 4 waves; each wave computes
// 4 rows at once so each ds_read of W feeds 4 FMAs. Lane j owns column j
// (Wl[k*64+j]: consecutive lanes -> consecutive banks, 2-way aliasing = free).
// ---------------------------------------------------------------------------
__global__ void __launch_bounds__(256) gemm_kernel(
        const float* __restrict__ h, const float* __restrict__ W,
        const float* __restrict__ deg_src, float* __restrict__ m, int n_nodes) {
    __shared__ float Wl[IN_DIM * OUT_DIM];  // 64 KB
    for (int i = threadIdx.x; i < IN_DIM * OUT_DIM / 4; i += blockDim.x) {
        ((float4*)Wl)[i] = ((const float4*)W)[i];
    }
    __syncthreads();

    const int wave = threadIdx.x >> 6;
    const int lane = threadIdx.x & 63;
    const int rowBase = (blockIdx.x * 4 + wave) * 4;
    if (rowBase >= n_nodes) return;

    const float4* h4 = (const float4*)h;
    const int ld4 = IN_DIM / 4;

    if (rowBase + 3 < n_nodes) {
        float acc0 = 0.f, acc1 = 0.f, acc2 = 0.f, acc3 = 0.f;
        #pragma unroll 4
        for (int k4 = 0; k4 < ld4; ++k4) {
            float4 h0 = h4[(rowBase + 0) * ld4 + k4];  // broadcast loads
            float4 h1 = h4[(rowBase + 1) * ld4 + k4];
            float4 h2 = h4[(rowBase + 2) * ld4 + k4];
            float4 h3 = h4[(rowBase + 3) * ld4 + k4];
            int k0 = k4 * 4;
            float w0 = Wl[(k0 + 0) * OUT_DIM + lane];
            float w1 = Wl[(k0 + 1) * OUT_DIM + lane];
            float w2 = Wl[(k0 + 2) * OUT_DIM + lane];
            float w3 = Wl[(k0 + 3) * OUT_DIM + lane];
            acc0 += h0.x * w0 + h0.y * w1 + h0.z * w2 + h0.w * w3;
            acc1 += h1.x * w0 + h1.y * w1 + h1.z * w2 + h1.w * w3;
            acc2 += h2.x * w0 + h2.y * w1 + h2.z * w2 + h2.w * w3;
            acc3 += h3.x * w0 + h3.y * w1 + h3.z * w2 + h3.w * w3;
        }
        float n0 = rsqrtf(fmaxf(deg_src[rowBase + 0], 1.0f));
        float n1 = rsqrtf(fmaxf(deg_src[rowBase + 1], 1.0f));
        float n2 = rsqrtf(fmaxf(deg_src[rowBase + 2], 1.0f));
        float n3 = rsqrtf(fmaxf(deg_src[rowBase + 3], 1.0f));
        m[(size_t)(rowBase + 0) * OUT_DIM + lane] = acc0 * n0;
        m[(size_t)(rowBase + 1) * OUT_DIM + lane] = acc1 * n1;
        m[(size_t)(rowBase + 2) * OUT_DIM + lane] = acc2 * n2;
        m[(size_t)(rowBase + 3) * OUT_DIM + lane] = acc3 * n3;
    } else {
        // tail (not hit for n_nodes=100000 but keep generic)
        for (int r = rowBase; r < n_nodes; ++r) {
            float acc = 0.f;
            for (int k = 0; k < IN_DIM; ++k)
                acc += h[(size_t)r * IN_DIM + k] * Wl[k * OUT_DIM + lane];
            float nr = rsqrtf(fmaxf(deg_src[r], 1.0f));
            m[(size_t)r * OUT_DIM + lane] = acc * nr;
        }
    }
}

// ---------------------------------------------------------------------------
// K3: edge-parallel scatter-add SpMM. One wave per edge; lane j moves one
// float. Gather reads of m[src] are 256B/wave coalesced (L2/L3-served);
// writes are fp32 atomics into out[dst].
// ---------------------------------------------------------------------------
__global__ void spmm_kernel(const int* __restrict__ src, const int* __restrict__ dst,
                            const float* __restrict__ m, float* __restrict__ out,
                            long long n_edges) {
    long long t = (long long)blockIdx.x * blockDim.x + threadIdx.x;
    long long e = t >> 6;
    int j = (int)(t & 63);
    if (e < n_edges) {
        int s = src[e];
        int d = dst[e];
        float v = m[(size_t)s * OUT_DIM + j];
        atomicAdd(&out[(size_t)d * OUT_DIM + j], v);
    }
}

// ---------------------------------------------------------------------------
// K4: out = log_softmax(agg * norm_dst + b) in-place. One wave per row,
// shuffle butterfly reductions over the 64 classes.
// ---------------------------------------------------------------------------
__global__ void finalize_kernel(float* __restrict__ out, const float* __restrict__ deg_dst,
                                const float* __restrict__ b, int n_nodes) {
    const int wave = threadIdx.x >> 6;
    const int lane = threadIdx.x & 63;
    const int row = blockIdx.x * 4 + wave;
    if (row >= n_nodes) return;

    float nd = rsqrtf(fmaxf(deg_dst[row], 1.0f));
    float x = out[(size_t)row * OUT_DIM + lane] * nd + b[lane];

    float mx = x;
    #pragma unroll
    for (int o = 32; o > 0; o >>= 1) mx = fmaxf(mx, __shfl_xor(mx, o, 64));
    float ex = expf(x - mx);
    float s = ex;
    #pragma unroll
    for (int o = 32; o > 0; o >>= 1) s += __shfl_xor(s, o, 64);
    out[(size_t)row * OUT_DIM + lane] = x - mx - logf(s);
}

// ---------------------------------------------------------------------------
extern "C" void kernel_launch(void* const* d_in, const int* in_sizes, int n_in,
                              void* d_out, int out_size, void* d_ws, size_t ws_size,
                              hipStream_t stream) {
    const float* h = (const float*)d_in[0];
    const float* W = (const float*)d_in[1];
    const float* b = (const float*)d_in[2];
    const int* edges = (const int*)d_in[3];

    const int out_dim = in_sizes[2];            // 64
    const int in_dim  = in_sizes[1] / out_dim;  // 256
    const int n_nodes = in_sizes[0] / in_dim;   // 100000
    const int n_edges = in_sizes[3] / 2;        // 3200000

    const int* src = edges;
    const int* dst = edges + n_edges;

    float* ws = (float*)d_ws;
    float* deg_src = ws;                 // [n_nodes]
    float* deg_dst = ws + n_nodes;       // [n_nodes]
    float* m       = ws + 2 * (size_t)n_nodes;  // [n_nodes * 64]
    float* out     = (float*)d_out;

    // zero accumulators (d_out/d_ws are poisoned 0xAA before every launch)
    hipMemsetAsync(deg_src, 0, 2 * (size_t)n_nodes * sizeof(float), stream);
    hipMemsetAsync(out, 0, (size_t)n_nodes * out_dim * sizeof(float), stream);

    deg_kernel<<<(n_edges + 255) / 256, 256, 0, stream>>>(src, dst, deg_src, deg_dst, n_edges);

    gemm_kernel<<<(n_nodes + 15) / 16, 256, 0, stream>>>(h, W, deg_src, m, n_nodes);

    long long tot = (long long)n_edges * 64;
    spmm_kernel<<<(unsigned)((tot + 255) / 256), 256, 0, stream>>>(src, dst, m, out, n_edges);

    finalize_kernel<<<(n_nodes + 3) / 4, 256, 0, stream>>>(out, deg_dst, b, n_nodes);
}

// Round 3
// 1088.270 us; speedup vs baseline: 1.3345x; 1.3345x over previous
//
#include <hip/hip_runtime.h>
#include <math.h>

#define IN_DIM 256
#define OUT_DIM 64
#define SCAN_CHUNK 1024   // elements per block in the scan (256 threads x 4)

// ---------------------------------------------------------------------------
// K1: integer degree histogram. One thread per edge; 2 int atomics.
// ---------------------------------------------------------------------------
__global__ void deg_kernel(const int* __restrict__ src, const int* __restrict__ dst,
                           int* __restrict__ out_deg, int* __restrict__ in_deg,
                           int n_edges) {
    int e = blockIdx.x * blockDim.x + threadIdx.x;
    if (e < n_edges) {
        atomicAdd(&out_deg[src[e]], 1);
        atomicAdd(&in_deg[dst[e]], 1);
    }
}

// ---------------------------------------------------------------------------
// K2a: per-chunk sums of in_deg (chunk = 1024 elements).
// ---------------------------------------------------------------------------
__global__ void __launch_bounds__(256) scan_sums_kernel(
        const int* __restrict__ in_deg, int* __restrict__ chunk_sums, int n) {
    const int t = threadIdx.x;
    const int base = blockIdx.x * SCAN_CHUNK;
    int s = 0;
    for (int i = t; i < SCAN_CHUNK; i += 256) {
        int idx = base + i;
        s += (idx < n) ? in_deg[idx] : 0;
    }
    #pragma unroll
    for (int o = 32; o > 0; o >>= 1) s += __shfl_down(s, o, 64);
    __shared__ int wsum[4];
    if ((t & 63) == 0) wsum[t >> 6] = s;
    __syncthreads();
    if (t == 0) chunk_sums[blockIdx.x] = wsum[0] + wsum[1] + wsum[2] + wsum[3];
}

// ---------------------------------------------------------------------------
// K2b: exclusive scan of chunk sums (single tiny block; ~98 values) and write
// row_start[n] = total edge count.
// ---------------------------------------------------------------------------
__global__ void scan_chunks_kernel(int* __restrict__ chunk_sums, int nchunks,
                                   int* __restrict__ row_start, int n) {
    if (threadIdx.x == 0 && blockIdx.x == 0) {
        int acc = 0;
        for (int i = 0; i < nchunks; ++i) {
            int v = chunk_sums[i];
            chunk_sums[i] = acc;
            acc += v;
        }
        row_start[n] = acc;
    }
}

// ---------------------------------------------------------------------------
// K2c: per-chunk exclusive scan -> row_start and cursor (copy).
// Each thread owns 4 consecutive elements.
// ---------------------------------------------------------------------------
__global__ void __launch_bounds__(256) scan_final_kernel(
        const int* __restrict__ in_deg, const int* __restrict__ chunk_sums,
        int* __restrict__ row_start, int* __restrict__ cursor, int n) {
    const int t = threadIdx.x;
    const int lane = t & 63;
    const int wave = t >> 6;
    const int idx = blockIdx.x * SCAN_CHUNK + t * 4;

    int v0 = (idx + 0 < n) ? in_deg[idx + 0] : 0;
    int v1 = (idx + 1 < n) ? in_deg[idx + 1] : 0;
    int v2 = (idx + 2 < n) ? in_deg[idx + 2] : 0;
    int v3 = (idx + 3 < n) ? in_deg[idx + 3] : 0;
    int s = v0 + v1 + v2 + v3;

    // inclusive wave scan of per-thread sums
    int sc = s;
    #pragma unroll
    for (int o = 1; o < 64; o <<= 1) {
        int u = __shfl_up(sc, o, 64);
        if (lane >= o) sc += u;
    }
    __shared__ int wsum[4];
    if (lane == 63) wsum[wave] = sc;
    __syncthreads();
    int waveoff = 0;
    for (int w = 0; w < wave; ++w) waveoff += wsum[w];

    int ex = sc - s + waveoff + chunk_sums[blockIdx.x];  // exclusive prefix

    if (idx + 0 < n) { row_start[idx + 0] = ex;               cursor[idx + 0] = ex; }
    ex += v0;
    if (idx + 1 < n) { row_start[idx + 1] = ex;               cursor[idx + 1] = ex; }
    ex += v1;
    if (idx + 2 < n) { row_start[idx + 2] = ex;               cursor[idx + 2] = ex; }
    ex += v2;
    if (idx + 3 < n) { row_start[idx + 3] = ex;               cursor[idx + 3] = ex; }
}

// ---------------------------------------------------------------------------
// K3: bin edges into CSR-by-dst. One thread per edge.
// ---------------------------------------------------------------------------
__global__ void bin_kernel(const int* __restrict__ src, const int* __restrict__ dst,
                           int* __restrict__ cursor, int* __restrict__ csr_src,
                           int n_edges) {
    int e = blockIdx.x * blockDim.x + threadIdx.x;
    if (e < n_edges) {
        int d = dst[e];
        int pos = atomicAdd(&cursor[d], 1);
        csr_src[pos] = src[e];
    }
}

// ---------------------------------------------------------------------------
// K4: m[row] = (h[row] @ W) * rsqrt(max(out_deg[row],1)).
// W staged in LDS (64 KB). 4 waves/block, 4 rows per wave pass.
// ---------------------------------------------------------------------------
__global__ void __launch_bounds__(256) gemm_kernel(
        const float* __restrict__ h, const float* __restrict__ W,
        const int* __restrict__ out_deg, float* __restrict__ m, int n_nodes) {
    __shared__ float Wl[IN_DIM * OUT_DIM];  // 64 KB
    for (int i = threadIdx.x; i < IN_DIM * OUT_DIM / 4; i += blockDim.x) {
        ((float4*)Wl)[i] = ((const float4*)W)[i];
    }
    __syncthreads();

    const int wave = threadIdx.x >> 6;
    const int lane = threadIdx.x & 63;
    const int rowBase = (blockIdx.x * 4 + wave) * 4;
    if (rowBase >= n_nodes) return;

    const float4* h4 = (const float4*)h;
    const int ld4 = IN_DIM / 4;

    if (rowBase + 3 < n_nodes) {
        float acc0 = 0.f, acc1 = 0.f, acc2 = 0.f, acc3 = 0.f;
        #pragma unroll 4
        for (int k4 = 0; k4 < ld4; ++k4) {
            float4 h0 = h4[(rowBase + 0) * ld4 + k4];
            float4 h1 = h4[(rowBase + 1) * ld4 + k4];
            float4 h2 = h4[(rowBase + 2) * ld4 + k4];
            float4 h3 = h4[(rowBase + 3) * ld4 + k4];
            int k0 = k4 * 4;
            float w0 = Wl[(k0 + 0) * OUT_DIM + lane];
            float w1 = Wl[(k0 + 1) * OUT_DIM + lane];
            float w2 = Wl[(k0 + 2) * OUT_DIM + lane];
            float w3 = Wl[(k0 + 3) * OUT_DIM + lane];
            acc0 += h0.x * w0 + h0.y * w1 + h0.z * w2 + h0.w * w3;
            acc1 += h1.x * w0 + h1.y * w1 + h1.z * w2 + h1.w * w3;
            acc2 += h2.x * w0 + h2.y * w1 + h2.z * w2 + h2.w * w3;
            acc3 += h3.x * w0 + h3.y * w1 + h3.z * w2 + h3.w * w3;
        }
        float n0 = rsqrtf(fmaxf((float)out_deg[rowBase + 0], 1.0f));
        float n1 = rsqrtf(fmaxf((float)out_deg[rowBase + 1], 1.0f));
        float n2 = rsqrtf(fmaxf((float)out_deg[rowBase + 2], 1.0f));
        float n3 = rsqrtf(fmaxf((float)out_deg[rowBase + 3], 1.0f));
        m[(size_t)(rowBase + 0) * OUT_DIM + lane] = acc0 * n0;
        m[(size_t)(rowBase + 1) * OUT_DIM + lane] = acc1 * n1;
        m[(size_t)(rowBase + 2) * OUT_DIM + lane] = acc2 * n2;
        m[(size_t)(rowBase + 3) * OUT_DIM + lane] = acc3 * n3;
    } else {
        for (int r = rowBase; r < n_nodes; ++r) {
            float acc = 0.f;
            for (int k = 0; k < IN_DIM; ++k)
                acc += h[(size_t)r * IN_DIM + k] * Wl[k * OUT_DIM + lane];
            float nr = rsqrtf(fmaxf((float)out_deg[r], 1.0f));
            m[(size_t)r * OUT_DIM + lane] = acc * nr;
        }
    }
}

// ---------------------------------------------------------------------------
// K5: CSR gather per dst row + fused norm_dst + bias + log_softmax.
// One wave per row (lane = class j); unrolled x4 to keep 4 gathers in flight.
// Writes each output row exactly once -> no atomics, minimal WRITE_SIZE.
// ---------------------------------------------------------------------------
__global__ void __launch_bounds__(256) gather_kernel(
        const int* __restrict__ row_start, const int* __restrict__ csr_src,
        const float* __restrict__ m, const int* __restrict__ in_deg,
        const float* __restrict__ b, float* __restrict__ out, int n_nodes) {
    const int wave = threadIdx.x >> 6;
    const int lane = threadIdx.x & 63;
    const int row = blockIdx.x * 4 + wave;
    if (row >= n_nodes) return;

    const int beg = row_start[row];
    const int end = row_start[row + 1];

    float acc = 0.f;
    int i = beg;
    for (; i + 4 <= end; i += 4) {
        int s0 = csr_src[i + 0];
        int s1 = csr_src[i + 1];
        int s2 = csr_src[i + 2];
        int s3 = csr_src[i + 3];
        float v0 = m[(size_t)s0 * OUT_DIM + lane];
        float v1 = m[(size_t)s1 * OUT_DIM + lane];
        float v2 = m[(size_t)s2 * OUT_DIM + lane];
        float v3 = m[(size_t)s3 * OUT_DIM + lane];
        acc += v0; acc += v1; acc += v2; acc += v3;
    }
    for (; i < end; ++i) acc += m[(size_t)csr_src[i] * OUT_DIM + lane];

    float nd = rsqrtf(fmaxf((float)in_deg[row], 1.0f));
    float x = acc * nd + b[lane];

    float mx = x;
    #pragma unroll
    for (int o = 32; o > 0; o >>= 1) mx = fmaxf(mx, __shfl_xor(mx, o, 64));
    float ex = expf(x - mx);
    float s = ex;
    #pragma unroll
    for (int o = 32; o > 0; o >>= 1) s += __shfl_xor(s, o, 64);
    out[(size_t)row * OUT_DIM + lane] = x - mx - logf(s);
}

// ---------------------------------------------------------------------------
static inline size_t align16(size_t x) { return (x + 15) & ~(size_t)15; }

extern "C" void kernel_launch(void* const* d_in, const int* in_sizes, int n_in,
                              void* d_out, int out_size, void* d_ws, size_t ws_size,
                              hipStream_t stream) {
    const float* h = (const float*)d_in[0];
    const float* W = (const float*)d_in[1];
    const float* b = (const float*)d_in[2];
    const int* edges = (const int*)d_in[3];

    const int out_dim = in_sizes[2];            // 64
    const int in_dim  = in_sizes[1] / out_dim;  // 256
    const int n_nodes = in_sizes[0] / in_dim;   // 100000
    const int n_edges = in_sizes[3] / 2;        // 3200000

    const int* src = edges;
    const int* dst = edges + n_edges;

    float* out = (float*)d_out;

    // workspace carve-up (16B aligned slices)
    char* ws = (char*)d_ws;
    size_t off = 0;
    int* in_deg     = (int*)(ws + off); off = align16(off + (size_t)n_nodes * 4);
    int* out_deg    = (int*)(ws + off); off = align16(off + (size_t)n_nodes * 4);
    int* row_start  = (int*)(ws + off); off = align16(off + (size_t)(n_nodes + 1) * 4);
    int* cursor     = (int*)(ws + off); off = align16(off + (size_t)n_nodes * 4);
    int* chunk_sums = (int*)(ws + off); off = align16(off + 256 * 4);
    float* m        = (float*)(ws + off); off = align16(off + (size_t)n_nodes * OUT_DIM * 4);
    int* csr_src    = (int*)(ws + off); off = align16(off + (size_t)n_edges * 4);

    const int nchunks = (n_nodes + SCAN_CHUNK - 1) / SCAN_CHUNK;

    // zero the degree histograms (ws is poisoned 0xAA before every launch)
    (void)hipMemsetAsync(in_deg, 0, (size_t)n_nodes * sizeof(int), stream);
    (void)hipMemsetAsync(out_deg, 0, (size_t)n_nodes * sizeof(int), stream);

    deg_kernel<<<(n_edges + 255) / 256, 256, 0, stream>>>(src, dst, out_deg, in_deg, n_edges);

    scan_sums_kernel<<<nchunks, 256, 0, stream>>>(in_deg, chunk_sums, n_nodes);
    scan_chunks_kernel<<<1, 64, 0, stream>>>(chunk_sums, nchunks, row_start, n_nodes);
    scan_final_kernel<<<nchunks, 256, 0, stream>>>(in_deg, chunk_sums, row_start, cursor, n_nodes);

    bin_kernel<<<(n_edges + 255) / 256, 256, 0, stream>>>(src, dst, cursor, csr_src, n_edges);

    gemm_kernel<<<(n_nodes + 15) / 16, 256, 0, stream>>>(h, W, out_deg, m, n_nodes);

    gather_kernel<<<(n_nodes + 3) / 4, 256, 0, stream>>>(row_start, csr_src, m, in_deg, b, out, n_nodes);
}

// Round 4
// 1022.131 us; speedup vs baseline: 1.4208x; 1.0647x over previous
//
#include <hip/hip_runtime.h>
#include <math.h>

#define IN_DIM 256
#define OUT_DIM 64
#define SCAN_CHUNK 1024   // elements per block in the scan (256 threads x 4)
#define GEMM_BLOCKS 512   // 2 blocks/CU (64 KB LDS each)

// ---------------------------------------------------------------------------
// K1: integer degree histogram. One thread per edge; 2 int atomics.
// ---------------------------------------------------------------------------
__global__ void deg_kernel(const int* __restrict__ src, const int* __restrict__ dst,
                           int* __restrict__ out_deg, int* __restrict__ in_deg,
                           int n_edges) {
    int e = blockIdx.x * blockDim.x + threadIdx.x;
    if (e < n_edges) {
        atomicAdd(&out_deg[src[e]], 1);
        atomicAdd(&in_deg[dst[e]], 1);
    }
}

// ---------------------------------------------------------------------------
// K2a: per-chunk sums of in_deg (chunk = 1024 elements).
// ---------------------------------------------------------------------------
__global__ void __launch_bounds__(256) scan_sums_kernel(
        const int* __restrict__ in_deg, int* __restrict__ chunk_sums, int n) {
    const int t = threadIdx.x;
    const int base = blockIdx.x * SCAN_CHUNK;
    int s = 0;
    for (int i = t; i < SCAN_CHUNK; i += 256) {
        int idx = base + i;
        s += (idx < n) ? in_deg[idx] : 0;
    }
    #pragma unroll
    for (int o = 32; o > 0; o >>= 1) s += __shfl_down(s, o, 64);
    __shared__ int wsum[4];
    if ((t & 63) == 0) wsum[t >> 6] = s;
    __syncthreads();
    if (t == 0) chunk_sums[blockIdx.x] = wsum[0] + wsum[1] + wsum[2] + wsum[3];
}

// ---------------------------------------------------------------------------
// K2b: exclusive scan of chunk sums (single tiny block) + total.
// ---------------------------------------------------------------------------
__global__ void scan_chunks_kernel(int* __restrict__ chunk_sums, int nchunks,
                                   int* __restrict__ row_start, int n) {
    if (threadIdx.x == 0 && blockIdx.x == 0) {
        int acc = 0;
        for (int i = 0; i < nchunks; ++i) {
            int v = chunk_sums[i];
            chunk_sums[i] = acc;
            acc += v;
        }
        row_start[n] = acc;
    }
}

// ---------------------------------------------------------------------------
// K2c: per-chunk exclusive scan -> row_start and cursor (copy).
// ---------------------------------------------------------------------------
__global__ void __launch_bounds__(256) scan_final_kernel(
        const int* __restrict__ in_deg, const int* __restrict__ chunk_sums,
        int* __restrict__ row_start, int* __restrict__ cursor, int n) {
    const int t = threadIdx.x;
    const int lane = t & 63;
    const int wave = t >> 6;
    const int idx = blockIdx.x * SCAN_CHUNK + t * 4;

    int v0 = (idx + 0 < n) ? in_deg[idx + 0] : 0;
    int v1 = (idx + 1 < n) ? in_deg[idx + 1] : 0;
    int v2 = (idx + 2 < n) ? in_deg[idx + 2] : 0;
    int v3 = (idx + 3 < n) ? in_deg[idx + 3] : 0;
    int s = v0 + v1 + v2 + v3;

    int sc = s;
    #pragma unroll
    for (int o = 1; o < 64; o <<= 1) {
        int u = __shfl_up(sc, o, 64);
        if (lane >= o) sc += u;
    }
    __shared__ int wsum[4];
    if (lane == 63) wsum[wave] = sc;
    __syncthreads();
    int waveoff = 0;
    for (int w = 0; w < wave; ++w) waveoff += wsum[w];

    int ex = sc - s + waveoff + chunk_sums[blockIdx.x];

    if (idx + 0 < n) { row_start[idx + 0] = ex; cursor[idx + 0] = ex; }
    ex += v0;
    if (idx + 1 < n) { row_start[idx + 1] = ex; cursor[idx + 1] = ex; }
    ex += v1;
    if (idx + 2 < n) { row_start[idx + 2] = ex; cursor[idx + 2] = ex; }
    ex += v2;
    if (idx + 3 < n) { row_start[idx + 3] = ex; cursor[idx + 3] = ex; }
}

// ---------------------------------------------------------------------------
// K3: bin edges into CSR-by-dst. One thread per edge.
// ---------------------------------------------------------------------------
__global__ void bin_kernel(const int* __restrict__ src, const int* __restrict__ dst,
                           int* __restrict__ cursor, int* __restrict__ csr_src,
                           int n_edges) {
    int e = blockIdx.x * blockDim.x + threadIdx.x;
    if (e < n_edges) {
        int d = dst[e];
        int pos = atomicAdd(&cursor[d], 1);
        csr_src[pos] = src[e];
    }
}

// ---------------------------------------------------------------------------
// K4: m[row] = (h[row] @ W) * rsqrt(max(out_deg[row],1)).
// Persistent: W staged in LDS ONCE per block (512 blocks = 2/CU), grid-stride
// over 8-row tiles per wave. rowBase forced wave-uniform (readfirstlane) so
// h loads use scalar/uniform addressing; 4 ds_reads of W feed 32 FMAs.
// ---------------------------------------------------------------------------
__global__ void __launch_bounds__(256) gemm_kernel(
        const float* __restrict__ h, const float* __restrict__ W,
        const int* __restrict__ out_deg, float* __restrict__ m, int n_nodes) {
    __shared__ float Wl[IN_DIM * OUT_DIM];  // 64 KB
    {
        const float4* W4 = (const float4*)W;
        float4* Wl4 = (float4*)Wl;
        #pragma unroll
        for (int i = 0; i < (IN_DIM * OUT_DIM / 4) / 256; ++i)
            Wl4[threadIdx.x + i * 256] = W4[threadIdx.x + i * 256];
    }
    __syncthreads();

    const int lane = threadIdx.x & 63;
    const int waveId = (blockIdx.x << 2) | (threadIdx.x >> 6);
    const int nWaves = gridDim.x << 2;

    const int nTiles = n_nodes >> 3;  // full 8-row tiles
    for (int tile = waveId; tile < nTiles; tile += nWaves) {
        const int rowBase = __builtin_amdgcn_readfirstlane(tile << 3);
        const float4* __restrict__ hp = (const float4*)(h + (size_t)rowBase * IN_DIM);
        float acc[8] = {0.f, 0.f, 0.f, 0.f, 0.f, 0.f, 0.f, 0.f};

        #pragma unroll 2
        for (int k4 = 0; k4 < IN_DIM / 4; ++k4) {
            float w0 = Wl[(k4 * 4 + 0) * OUT_DIM + lane];
            float w1 = Wl[(k4 * 4 + 1) * OUT_DIM + lane];
            float w2 = Wl[(k4 * 4 + 2) * OUT_DIM + lane];
            float w3 = Wl[(k4 * 4 + 3) * OUT_DIM + lane];
            #pragma unroll
            for (int r = 0; r < 8; ++r) {
                float4 hv = hp[r * (IN_DIM / 4) + k4];
                acc[r] += hv.x * w0 + hv.y * w1 + hv.z * w2 + hv.w * w3;
            }
        }

        #pragma unroll
        for (int r = 0; r < 8; ++r) {
            float nr = rsqrtf(fmaxf((float)out_deg[rowBase + r], 1.0f));
            m[(size_t)(rowBase + r) * OUT_DIM + lane] = acc[r] * nr;
        }
    }

    // tail rows (n_nodes % 8)
    for (int r = nTiles * 8 + waveId; r < n_nodes; r += nWaves) {
        float acc = 0.f;
        for (int k = 0; k < IN_DIM; ++k)
            acc += h[(size_t)r * IN_DIM + k] * Wl[k * OUT_DIM + lane];
        float nr = rsqrtf(fmaxf((float)out_deg[r], 1.0f));
        m[(size_t)r * OUT_DIM + lane] = acc * nr;
    }
}

// ---------------------------------------------------------------------------
// K5: CSR gather per dst row + fused norm_dst + bias + log_softmax.
// One wave per row; writes each output row exactly once.
// ---------------------------------------------------------------------------
__global__ void __launch_bounds__(256) gather_kernel(
        const int* __restrict__ row_start, const int* __restrict__ csr_src,
        const float* __restrict__ m, const int* __restrict__ in_deg,
        const float* __restrict__ b, float* __restrict__ out, int n_nodes) {
    const int wave = threadIdx.x >> 6;
    const int lane = threadIdx.x & 63;
    const int row = blockIdx.x * 4 + wave;
    if (row >= n_nodes) return;

    const int beg = row_start[row];
    const int end = row_start[row + 1];

    float acc = 0.f;
    int i = beg;
    for (; i + 4 <= end; i += 4) {
        int s0 = csr_src[i + 0];
        int s1 = csr_src[i + 1];
        int s2 = csr_src[i + 2];
        int s3 = csr_src[i + 3];
        float v0 = m[(size_t)s0 * OUT_DIM + lane];
        float v1 = m[(size_t)s1 * OUT_DIM + lane];
        float v2 = m[(size_t)s2 * OUT_DIM + lane];
        float v3 = m[(size_t)s3 * OUT_DIM + lane];
        acc += v0; acc += v1; acc += v2; acc += v3;
    }
    for (; i < end; ++i) acc += m[(size_t)csr_src[i] * OUT_DIM + lane];

    float nd = rsqrtf(fmaxf((float)in_deg[row], 1.0f));
    float x = acc * nd + b[lane];

    float mx = x;
    #pragma unroll
    for (int o = 32; o > 0; o >>= 1) mx = fmaxf(mx, __shfl_xor(mx, o, 64));
    float ex = expf(x - mx);
    float s = ex;
    #pragma unroll
    for (int o = 32; o > 0; o >>= 1) s += __shfl_xor(s, o, 64);
    out[(size_t)row * OUT_DIM + lane] = x - mx - logf(s);
}

// ---------------------------------------------------------------------------
static inline size_t align16(size_t x) { return (x + 15) & ~(size_t)15; }

extern "C" void kernel_launch(void* const* d_in, const int* in_sizes, int n_in,
                              void* d_out, int out_size, void* d_ws, size_t ws_size,
                              hipStream_t stream) {
    const float* h = (const float*)d_in[0];
    const float* W = (const float*)d_in[1];
    const float* b = (const float*)d_in[2];
    const int* edges = (const int*)d_in[3];

    const int out_dim = in_sizes[2];            // 64
    const int in_dim  = in_sizes[1] / out_dim;  // 256
    const int n_nodes = in_sizes[0] / in_dim;   // 100000
    const int n_edges = in_sizes[3] / 2;        // 3200000

    const int* src = edges;
    const int* dst = edges + n_edges;

    float* out = (float*)d_out;

    // workspace carve-up (16B aligned slices)
    char* ws = (char*)d_ws;
    size_t off = 0;
    int* in_deg     = (int*)(ws + off); off = align16(off + (size_t)n_nodes * 4);
    int* out_deg    = (int*)(ws + off); off = align16(off + (size_t)n_nodes * 4);
    int* row_start  = (int*)(ws + off); off = align16(off + (size_t)(n_nodes + 1) * 4);
    int* cursor     = (int*)(ws + off); off = align16(off + (size_t)n_nodes * 4);
    int* chunk_sums = (int*)(ws + off); off = align16(off + 256 * 4);
    float* m        = (float*)(ws + off); off = align16(off + (size_t)n_nodes * OUT_DIM * 4);
    int* csr_src    = (int*)(ws + off); off = align16(off + (size_t)n_edges * 4);

    const int nchunks = (n_nodes + SCAN_CHUNK - 1) / SCAN_CHUNK;

    (void)hipMemsetAsync(in_deg, 0, (size_t)n_nodes * sizeof(int), stream);
    (void)hipMemsetAsync(out_deg, 0, (size_t)n_nodes * sizeof(int), stream);

    deg_kernel<<<(n_edges + 255) / 256, 256, 0, stream>>>(src, dst, out_deg, in_deg, n_edges);

    scan_sums_kernel<<<nchunks, 256, 0, stream>>>(in_deg, chunk_sums, n_nodes);
    scan_chunks_kernel<<<1, 64, 0, stream>>>(chunk_sums, nchunks, row_start, n_nodes);
    scan_final_kernel<<<nchunks, 256, 0, stream>>>(in_deg, chunk_sums, row_start, cursor, n_nodes);

    bin_kernel<<<(n_edges + 255) / 256, 256, 0, stream>>>(src, dst, cursor, csr_src, n_edges);

    gemm_kernel<<<GEMM_BLOCKS, 256, 0, stream>>>(h, W, out_deg, m, n_nodes);

    gather_kernel<<<(n_nodes + 3) / 4, 256, 0, stream>>>(row_start, csr_src, m, in_deg, b, out, n_nodes);
}